// Round 5
// baseline (485.380 us; speedup 1.0000x reference)
//
#include <hip/hip_runtime.h>
#include <stdint.h>

// PRNG variant: 1 = jax_threefry_partitionable=True (JAX >= 0.4.36 default)
#ifndef JAX_THREEFRY_PARTITIONABLE
#define JAX_THREEFRY_PARTITIONABLE 1
#endif

#define N_SAMP 2000
#define L_VAR  10000
#define R_PERM 200
#define DOF_D  1989.0   // N - K - 1

#define KPAD   2048     // padded K (samples) for MFMA path
#define LPAD   10048    // padded L (157*64, = 314*32)
#define RPAD   256      // padded R (256 = 4 r-tiles of 64)

// ---------------- workspace layout (bytes) ----------------
// ---- fallback region (layout identical to round-2 kernel) ----
#define OFF_PKEYS  0UL
#define OFF_MI     1664UL
#define OFF_MINP   2464UL
#define OFF_XT     2560UL
#define OFF_XTGP   82560UL     // fallback only
#define OFF_GGP    2082560UL   // fallback only
#define OFF_GG     2282560UL
#define OFF_YTY    2322560UL
#define OFF_S      2323392UL
#define OFF_YT     2324224UL   // fallback only (big path overlaps with YHI)
#define WS_OLD     3924224UL
// ---- big-ws (MFMA) region; overlaps fallback-only scratch, total 93.7 MB ----
#define OFF_GGP2   82560UL     // float[16][10048] = 643,072 (over fallback XTGP)
#define OFF_RGG    725632UL    // float[10048] -> ends 765,824
#define OFF_YHI    2324224UL   // u16[256][2048] = 1,048,576 (over fallback YT)
#define OFF_XTGP2  3924224UL   // float[16][10][10048] = 6,430,720
#define OFF_YLO    10354944UL  // u16[256][2048] = 1,048,576
#define OFF_GTHI   11403520UL  // u16[10048][2048] = 41,156,608
#define OFF_GTLO   52560128UL  // u16[10048][2048] -> ends 93,716,736
#define WS_BIG     95186432UL  // harness ws_size known >= this (round 3/4 ran big path)

typedef __attribute__((ext_vector_type(8))) short short8v;   // 8 bf16
typedef __attribute__((ext_vector_type(4))) float float4v;   // MFMA acc

// ---------------- threefry2x32, JAX-exact ----------------
__device__ __forceinline__ uint32_t rotl32(uint32_t v, int d) {
  return (v << d) | (v >> (32 - d));
}
__device__ __forceinline__ uint2 tf2(uint32_t k0, uint32_t k1, uint32_t x0, uint32_t x1) {
  uint32_t ks2 = k0 ^ k1 ^ 0x1BD11BDAu;
  x0 += k0; x1 += k1;
#define TF4(a,b,c,d) \
  x0 += x1; x1 = rotl32(x1,a); x1 ^= x0; \
  x0 += x1; x1 = rotl32(x1,b); x1 ^= x0; \
  x0 += x1; x1 = rotl32(x1,c); x1 ^= x0; \
  x0 += x1; x1 = rotl32(x1,d); x1 ^= x0;
  TF4(13,15,26,6)  x0 += k1;  x1 += ks2 + 1u;
  TF4(17,29,16,24) x0 += ks2; x1 += k0 + 2u;
  TF4(13,15,26,6)  x0 += k0;  x1 += k1 + 3u;
  TF4(17,29,16,24) x0 += k1;  x1 += ks2 + 4u;
  TF4(13,15,26,6)  x0 += ks2; x1 += k0 + 5u;
#undef TF4
  return make_uint2(x0, x1);
}

__device__ __forceinline__ void gen_pkeys(const int* seedp, unsigned* pkeys) {
  uint32_t khi = 0u, klo = (uint32_t)(*seedp);
  for (int r = 0; r < R_PERM; ++r) {
#if JAX_THREEFRY_PARTITIONABLE
    uint2 pk = tf2(khi, klo, 0u, 1u);
    uint2 nk = tf2(khi, klo, 0u, 0u);
#else
    uint2 t0 = tf2(khi, klo, 0u, 2u);
    uint2 t1 = tf2(khi, klo, 1u, 3u);
    uint2 nk = make_uint2(t0.x, t1.x);
    uint2 pk = make_uint2(t0.y, t1.y);
#endif
    pkeys[2 * r] = pk.x; pkeys[2 * r + 1] = pk.y;
    khi = nk.x; klo = nk.y;
  }
}

// ---------------- block reduce (256 threads) ----------------
__device__ __forceinline__ double breduce_add(double v, double* red, int tid) {
  red[tid] = v; __syncthreads();
  for (int off = 128; off > 0; off >>= 1) {
    if (tid < off) red[tid] += red[tid + off];
    __syncthreads();
  }
  double r = red[0]; __syncthreads();
  return r;
}

// ---------------- special functions (double) ----------------
__device__ double dg_digamma(double x) {
  if (!(x > 0.0)) return __builtin_nan("");
  double r = 0.0;
  while (x < 8.0) { r -= 1.0 / x; x += 1.0; }
  double t = 1.0 / x, t2 = t * t;
  double ser = t2 * (1.0/12.0 - t2*(1.0/120.0 - t2*(1.0/252.0 - t2*(1.0/240.0 - t2*(1.0/132.0)))));
  return r + log(x) - 0.5 * t - ser;
}
__device__ double dg_trigamma(double x) {
  if (!(x > 0.0)) return __builtin_nan("");
  double r = 0.0;
  while (x < 8.0) { r += 1.0 / (x * x); x += 1.0; }
  double t = 1.0 / x, t2 = t * t;
  double P = 1.0/6.0 - t2*(1.0/30.0 - t2*(1.0/42.0 - t2*(1.0/30.0 - t2*(5.0/66.0))));
  return r + t + 0.5 * t2 + t * t2 * P;
}
__device__ double dg_tetragamma(double x) {
  if (!(x > 0.0)) return __builtin_nan("");
  double r = 0.0;
  while (x < 8.0) { r -= 2.0 / (x * x * x); x += 1.0; }
  double t = 1.0 / x, t2 = t * t;
  double Q = 1.0 + t + 0.5*t2 - t2*t2*(1.0/6.0 - t2*(1.0/6.0 - t2*(3.0/10.0)));
  return r - t2 * Q;
}
__device__ double betacf_d(double a, double b, double x) {
  const double FPMIN = 1e-300, EPS = 3e-16;
  double qab = a + b, qap = a + 1.0, qam = a - 1.0;
  double c = 1.0, d = 1.0 - qab * x / qap;
  if (fabs(d) < FPMIN) d = FPMIN;
  d = 1.0 / d; double h = d;
  for (int m = 1; m <= 300; ++m) {
    int m2 = 2 * m;
    double aa = m * (b - m) * x / ((qam + m2) * (a + m2));
    d = 1.0 + aa * d; if (fabs(d) < FPMIN) d = FPMIN;
    c = 1.0 + aa / c; if (fabs(c) < FPMIN) c = FPMIN;
    d = 1.0 / d; double del = d * c; h *= del;
    aa = -(a + m) * (qab + m) * x / ((a + m2) * (qap + m2));
    d = 1.0 + aa * d; if (fabs(d) < FPMIN) d = FPMIN;
    c = 1.0 + aa / c; if (fabs(c) < FPMIN) c = FPMIN;
    d = 1.0 / d; del = d * c; h *= del;
    if (fabs(del - 1.0) < EPS) break;
  }
  return h;
}
__device__ double betainc_d(double a, double b, double x) {
  if (!(x > 0.0)) return 0.0;
  if (x >= 1.0) return 1.0;
  double lnbt = lgamma(a + b) - lgamma(a) - lgamma(b) + a * log(x) + b * log1p(-x);
  double bt = exp(lnbt);
  if (x < (a + 1.0) / (a + b + 2.0)) return bt * betacf_d(a, b, x) / a;
  else return 1.0 - bt * betacf_d(b, a, 1.0 - x) / b;
}

// ---------------- bitonic sort of 2048 u64 (== stable u32 sort) ----------------
__device__ __forceinline__ void bitonic2048(unsigned long long* arr, int tid) {
  for (int size = 2; size <= 2048; size <<= 1) {
    for (int stride = size >> 1; stride > 0; stride >>= 1) {
      __syncthreads();
      #pragma unroll 4
      for (int p = tid; p < 1024; p += 256) {
        int i = 2 * p - (p & (stride - 1));
        int j = i + stride;
        bool up = ((i & size) == 0);
        unsigned long long a = arr[i], b = arr[j];
        bool sw = up ? (a > b) : (a < b);
        if (sw) { arr[i] = b; arr[j] = a; }
      }
    }
  }
  __syncthreads();
}

__device__ __forceinline__ void fill_keys(unsigned long long* arr, uint32_t kx, uint32_t ky, int tid) {
#if JAX_THREEFRY_PARTITIONABLE
  for (int i = tid; i < 2048; i += 256) {
    if (i < 2000) {
      uint2 o = tf2(kx, ky, 0u, (uint32_t)i);
      uint32_t bits = o.x ^ o.y;
      arr[i] = (((unsigned long long)bits) << 11) | (unsigned long long)i;
    } else {
      arr[i] = ~0ull;
    }
  }
#else
  for (int j = tid; j < 1024; j += 256) {
    if (j < 1000) {
      uint2 o = tf2(kx, ky, (uint32_t)j, (uint32_t)(1000 + j));
      arr[j]        = (((unsigned long long)o.x) << 11) | (unsigned long long)j;
      arr[1000 + j] = (((unsigned long long)o.y) << 11) | (unsigned long long)(1000 + j);
    }
  }
  for (int i = 2000 + tid; i < 2048; i += 256) arr[i] = ~0ull;
#endif
}

__device__ __forceinline__ void tri_ab(int q, int& a, int& b) {
  int aa = 0, rem = q;
  while (rem >= 10 - aa) { rem -= 10 - aa; ++aa; }
  a = aa; b = aa + rem;
}

// split fp32 -> bf16 hi + bf16 lo (truncation split)
__device__ __forceinline__ void bf16split(float f, unsigned short& h, unsigned short& l) {
  unsigned u = __float_as_uint(f);
  h = (unsigned short)(u >> 16);
  float rem = f - __uint_as_float(u & 0xFFFF0000u);
  l = (unsigned short)(__float_as_uint(rem) >> 16);
}

// ================= KZ: zero bf16 Yt pad rows (big path) =======================
__global__ __launch_bounds__(256) void kz_pad(
    unsigned short* __restrict__ yhi, unsigned short* __restrict__ ylo) {
  int row = R_PERM + blockIdx.x;
  size_t base = (size_t)row * KPAD;
  for (int i = threadIdx.x; i < KPAD; i += 256) {
    yhi[base + i] = 0;
    ylo[base + i] = 0;
  }
}

// ================= K1: XtX + inverse (LDS GJ), min(obs_p), X^T ================
__global__ __launch_bounds__(256) void k1_setup(
    const float* __restrict__ X, const float* __restrict__ obs_p,
    float* __restrict__ Xt, double* __restrict__ Mi, float* __restrict__ minp) {
  int tid = threadIdx.x;
  if (blockIdx.x == 0) {
    __shared__ double xtx_sh[55];
    __shared__ double A[10][21];
    __shared__ int piv_sh;
    __shared__ double pv_sh;
    int wave = tid >> 6, lane = tid & 63;
    for (int q = wave; q < 55; q += 4) {
      int a, b; tri_ab(q, a, b);
      double acc = 0.0;
      for (int i = lane; i < N_SAMP; i += 64)
        acc += (double)X[i * 10 + a] * (double)X[i * 10 + b];
      for (int off = 32; off > 0; off >>= 1) acc += __shfl_xor(acc, off, 64);
      if (lane == 0) xtx_sh[q] = acc;
    }
    __syncthreads();
    if (tid < 200) {
      int r = tid / 20, j = tid % 20;
      double v;
      if (j < 10) {
        int a = r < j ? r : j;
        int b = r < j ? j : r;
        int q = 10 * a - a * (a - 1) / 2 + (b - a);
        v = xtx_sh[q];
      } else {
        v = (j - 10 == r) ? 1.0 : 0.0;
      }
      A[r][j] = v;
    }
    __syncthreads();
    int r_ = tid / 20, j_ = tid % 20;
    bool in200 = (tid < 200);
    for (int c = 0; c < 10; ++c) {
      if (tid == 0) {
        int piv = c; double best = fabs(A[c][c]);
        for (int r2 = c + 1; r2 < 10; ++r2)
          if (fabs(A[r2][c]) > best) { best = fabs(A[r2][c]); piv = r2; }
        piv_sh = piv;
      }
      __syncthreads();
      int piv = piv_sh;
      if (piv != c && tid < 20) {
        double t = A[c][tid]; A[c][tid] = A[piv][tid]; A[piv][tid] = t;
      }
      __syncthreads();
      if (tid == 0) pv_sh = A[c][c];
      __syncthreads();
      if (tid < 20) A[c][tid] *= (1.0 / pv_sh);
      __syncthreads();
      double f = 0.0, acj = 0.0;
      bool act = in200 && (r_ != c);
      if (act) { f = A[r_][c]; acj = A[c][j_]; }
      __syncthreads();
      if (act) A[r_][j_] -= f * acj;
      __syncthreads();
    }
    if (tid < 100) Mi[tid] = A[tid / 10][10 + (tid % 10)];
  } else if (blockIdx.x == 1) {
    __shared__ float redf[256];
    float m = 1e30f;
    for (int i = tid; i < L_VAR; i += 256) m = fminf(m, obs_p[i]);
    redf[tid] = m; __syncthreads();
    for (int off = 128; off > 0; off >>= 1) {
      if (tid < off) redf[tid] = fminf(redf[tid], redf[tid + off]);
      __syncthreads();
    }
    if (tid == 0) *minp = redf[0];
  } else {
    for (int idx = tid; idx < 10 * N_SAMP; idx += 256) {
      int k = idx / N_SAMP, i = idx - k * N_SAMP;
      Xt[idx] = X[i * 10 + k];
    }
  }
}

// ================= K2 (fallback): XtG/GG partials + key chain =================
__global__ __launch_bounds__(256) void k2_xtg(
    const float* __restrict__ G, const float* __restrict__ X,
    const int* __restrict__ seedp, float* __restrict__ XtGp,
    float* __restrict__ GGp, unsigned* __restrict__ pkeys) {
  if (blockIdx.x == 40) {
    if (blockIdx.y == 0 && threadIdx.x == 0) gen_pkeys(seedp, pkeys);
    return;
  }
  int l = blockIdx.x * 256 + threadIdx.x;
  bool valid = (l < L_VAR);
  int i0 = blockIdx.y * 400;
  float acc[10];
  #pragma unroll
  for (int k = 0; k < 10; ++k) acc[k] = 0.f;
  float g2 = 0.f;
  for (int i = i0; i < i0 + 400; ++i) {
    float g = valid ? G[(size_t)i * L_VAR + l] : 0.f;
    #pragma unroll
    for (int k = 0; k < 10; ++k) acc[k] = fmaf(g, X[i * 10 + k], acc[k]);
    g2 = fmaf(g, g, g2);
  }
  if (valid) {
    int part = blockIdx.y;
    #pragma unroll
    for (int k = 0; k < 10; ++k)
      XtGp[((size_t)part * 10 + k) * L_VAR + l] = acc[k];
    GGp[(size_t)part * L_VAR + l] = g2;
  }
}

// ===== K2T (big): G pass -> G^T bf16 hi/lo + XtG/GG partials + key chain =====
__global__ __launch_bounds__(256) void k2t_pass(
    const float* __restrict__ G, const float* __restrict__ X,
    const int* __restrict__ seedp,
    unsigned short* __restrict__ GTHI, unsigned short* __restrict__ GTLO,
    float* __restrict__ XtGp2, float* __restrict__ GGp2,
    unsigned* __restrict__ pkeys) {
  if (blockIdx.x == 157) {
    if (blockIdx.y == 0 && threadIdx.x == 0) gen_pkeys(seedp, pkeys);
    return;
  }
  __shared__ float T[128][69];
  __shared__ float Xsh[128][10];
  int tid = threadIdx.x;
  int l0 = blockIdx.x * 64, i0 = blockIdx.y * 128;
  for (int it = 0; it < 8; ++it) {
    int fi = it * 256 + tid;
    int row = fi >> 4, c4 = (fi & 15) * 4;
    int i = i0 + row, l = l0 + c4;
    float4 v = make_float4(0.f, 0.f, 0.f, 0.f);
    if (i < N_SAMP && l + 3 < L_VAR) v = *(const float4*)(G + (size_t)i * L_VAR + l);
    T[row][c4 + 0] = v.x; T[row][c4 + 1] = v.y; T[row][c4 + 2] = v.z; T[row][c4 + 3] = v.w;
  }
  for (int q = 0; q < 5; ++q) {
    int idx = q * 256 + tid;
    if (idx < 1280) {
      int row = idx / 10, k = idx - row * 10;
      int i = i0 + row;
      Xsh[row][k] = (i < N_SAMP) ? X[i * 10 + k] : 0.f;
    }
  }
  __syncthreads();
  {
    int w = tid >> 6, lam = tid & 63;
    int half = lam >> 5, i4 = (lam & 31) * 4;
    for (int g = 0; g < 8; ++g) {
      int lloc = g * 8 + w * 2 + half;
      float fv[4];
      fv[0] = T[i4 + 0][lloc]; fv[1] = T[i4 + 1][lloc];
      fv[2] = T[i4 + 2][lloc]; fv[3] = T[i4 + 3][lloc];
      ushort4 hv, lv;
      bf16split(fv[0], hv.x, lv.x);
      bf16split(fv[1], hv.y, lv.y);
      bf16split(fv[2], hv.z, lv.z);
      bf16split(fv[3], hv.w, lv.w);
      size_t idx = (size_t)(l0 + lloc) * KPAD + i0 + i4;
      *(ushort4*)(GTHI + idx) = hv;
      *(ushort4*)(GTLO + idx) = lv;
    }
  }
  int lc = tid & 63, iq = tid >> 6;
  float accx[10];
  #pragma unroll
  for (int k = 0; k < 10; ++k) accx[k] = 0.f;
  float g2 = 0.f;
  for (int j = 0; j < 32; ++j) {
    int i = iq * 32 + j;
    float tv = T[i][lc];
    g2 = fmaf(tv, tv, g2);
    #pragma unroll
    for (int k = 0; k < 10; ++k) accx[k] = fmaf(tv, Xsh[i][k], accx[k]);
  }
  __syncthreads();
  float* scr = &T[0][0];
  #pragma unroll
  for (int k = 0; k < 10; ++k) scr[(iq * 64 + lc) * 10 + k] = accx[k];
  scr[2560 + iq * 64 + lc] = g2;
  __syncthreads();
  for (int idx = tid; idx < 640; idx += 256) {
    int l = idx / 10, k = idx - l * 10;
    float t = scr[(0 * 64 + l) * 10 + k] + scr[(1 * 64 + l) * 10 + k]
            + scr[(2 * 64 + l) * 10 + k] + scr[(3 * 64 + l) * 10 + k];
    XtGp2[((size_t)blockIdx.y * 10 + k) * LPAD + l0 + l] = t;
  }
  if (tid < 64) {
    float s4 = scr[2560 + tid] + scr[2560 + 64 + tid] + scr[2560 + 128 + tid] + scr[2560 + 192 + tid];
    GGp2[(size_t)blockIdx.y * LPAD + l0 + tid] = s4;
  }
}

// ================= K3 (fallback) ==============================================
__global__ __launch_bounds__(256) void k3_gg(
    const float* __restrict__ XtGp, const float* __restrict__ GGp,
    const double* __restrict__ Mi, float* __restrict__ gg) {
  int l = blockIdx.x * 256 + threadIdx.x;
  if (l >= L_VAR) return;
  double t[10]; double g2 = 0.0;
  #pragma unroll
  for (int k = 0; k < 10; ++k) t[k] = 0.0;
  for (int part = 0; part < 5; ++part) {
    #pragma unroll
    for (int k = 0; k < 10; ++k)
      t[k] += (double)XtGp[((size_t)part * 10 + k) * L_VAR + l];
    g2 += (double)GGp[(size_t)part * L_VAR + l];
  }
  double corr = 0.0;
  #pragma unroll
  for (int k = 0; k < 10; ++k) {
    double a = 0.0;
    #pragma unroll
    for (int j = 0; j < 10; ++j) a += Mi[k * 10 + j] * t[j];
    corr += a * t[k];
  }
  gg[l] = (float)(g2 - corr);
}

// ================= K3T (big): gg + rgg from 16 partials =======================
__global__ __launch_bounds__(256) void k3t_gg(
    const float* __restrict__ XtGp2, const float* __restrict__ GGp2,
    const double* __restrict__ Mi, float* __restrict__ gg, float* __restrict__ rgg) {
  int l = blockIdx.x * 256 + threadIdx.x;
  if (l >= LPAD) return;
  double t[10]; double g2 = 0.0;
  #pragma unroll
  for (int k = 0; k < 10; ++k) t[k] = 0.0;
  for (int part = 0; part < 16; ++part) {
    #pragma unroll
    for (int k = 0; k < 10; ++k)
      t[k] += (double)XtGp2[((size_t)part * 10 + k) * LPAD + l];
    g2 += (double)GGp2[(size_t)part * LPAD + l];
  }
  double corr = 0.0;
  #pragma unroll
  for (int k = 0; k < 10; ++k) {
    double a = 0.0;
    #pragma unroll
    for (int j = 0; j < 10; ++j) a += Mi[k * 10 + j] * t[j];
    corr += a * t[k];
  }
  double v = g2 - corr;
  if (l < L_VAR) {
    gg[l] = (float)v;
    rgg[l] = (v > 0.0) ? (float)(1.0 / v) : 0.f;
  } else {
    rgg[l] = 0.f;
  }
}

// ================= K4: per-permutation shuffle + residualized Yt ==============
__global__ __launch_bounds__(256) void k4_perm(
    const float* __restrict__ y, const float* __restrict__ offs,
    const float* __restrict__ Xt, const unsigned* __restrict__ pkeys,
    const double* __restrict__ Mi, float* __restrict__ Yt,
    float* __restrict__ yty, unsigned* __restrict__ s,
    unsigned short* __restrict__ yhi, unsigned short* __restrict__ ylo) {
  __shared__ unsigned long long arr[2048];
  __shared__ unsigned short sig1[2048];
  __shared__ float yp[2000];
  __shared__ double red[256];
  __shared__ double mvd[10];
  __shared__ unsigned ksh[4];
  int r = blockIdx.x, tid = threadIdx.x;

  if (tid == 0) {
    uint32_t phi = pkeys[2 * r], plo = pkeys[2 * r + 1];
#if JAX_THREEFRY_PARTITIONABLE
    uint2 sub1 = tf2(phi, plo, 0u, 1u);
    uint2 key1 = tf2(phi, plo, 0u, 0u);
    uint2 sub2 = tf2(key1.x, key1.y, 0u, 1u);
#else
    uint2 a0 = tf2(phi, plo, 0u, 2u), a1 = tf2(phi, plo, 1u, 3u);
    uint2 key1 = make_uint2(a0.x, a1.x);
    uint2 sub1 = make_uint2(a0.y, a1.y);
    uint2 b0 = tf2(key1.x, key1.y, 0u, 2u), b1 = tf2(key1.x, key1.y, 1u, 3u);
    uint2 sub2 = make_uint2(b0.y, b1.y);
#endif
    ksh[0] = sub1.x; ksh[1] = sub1.y; ksh[2] = sub2.x; ksh[3] = sub2.y;
  }
  __syncthreads();
  uint32_t s1x = ksh[0], s1y = ksh[1], s2x = ksh[2], s2y = ksh[3];

  fill_keys(arr, s1x, s1y, tid);
  bitonic2048(arr, tid);
  for (int i = tid; i < 2048; i += 256) sig1[i] = (unsigned short)(arr[i] & 2047u);
  __syncthreads();
  fill_keys(arr, s2x, s2y, tid);
  bitonic2048(arr, tid);
  for (int i = tid; i < N_SAMP; i += 256) {
    int s2i = (int)(arr[i] & 2047u);
    int fin = (int)sig1[s2i];
    yp[i] = y[fin] - offs[i];
  }
  __syncthreads();

  double wloc[10];
  #pragma unroll
  for (int k = 0; k < 10; ++k) wloc[k] = 0.0;
  for (int i = tid; i < N_SAMP; i += 256) {
    double v = (double)yp[i];
    #pragma unroll
    for (int k = 0; k < 10; ++k) wloc[k] += (double)Xt[k * N_SAMP + i] * v;
  }
  double wfull[10];
  for (int k = 0; k < 10; ++k) wfull[k] = breduce_add(wloc[k], red, tid);
  if (tid == 0) {
    #pragma unroll
    for (int j = 0; j < 10; ++j) {
      double m = 0.0;
      #pragma unroll
      for (int k = 0; k < 10; ++k) m += Mi[j * 10 + k] * wfull[k];
      mvd[j] = m;
    }
  }
  __syncthreads();

  double acc = 0.0;
  for (int i = tid; i < N_SAMP; i += 256) {
    double d = (double)yp[i];
    #pragma unroll
    for (int k = 0; k < 10; ++k) d -= (double)Xt[k * N_SAMP + i] * mvd[k];
    float v = (float)d;
    if (Yt) Yt[(size_t)r * N_SAMP + i] = v;
    yp[i] = v;
    acc += (double)v * (double)v;
  }
  double tot = breduce_add(acc, red, tid);
  if (tid == 0) { yty[r] = (float)tot; s[r] = 0u; }

  if (yhi) {
    for (int i = tid; i < KPAD; i += 256) {
      float v = (i < N_SAMP) ? yp[i] : 0.f;
      unsigned short h, l;
      bf16split(v, h, l);
      yhi[(size_t)r * KPAD + i] = h;
      ylo[(size_t)r * KPAD + i] = l;
    }
  }
}

// ================= K5 (fallback): fp32 VALU GEMM ==============================
__global__ __launch_bounds__(256) void k5_gemm(
    const float* __restrict__ G, const float* __restrict__ Yt,
    const float* __restrict__ gg, unsigned* __restrict__ s) {
  __shared__ float As[16][64];
  __shared__ float Bs[16][68];
  int tid = threadIdx.x;
  int tx = tid & 15, ty = tid >> 4;
  int l0 = blockIdx.x * 64, r0 = blockIdx.y * 64;
  int a_row = tid >> 4;
  int a_col = (tid & 15) * 4;
  int b_row = tid >> 2;
  int b_col = (tid & 3) * 4;
  int gl = l0 + a_col;
  bool aval = (gl < L_VAR);
  int gr = r0 + b_row;
  bool bval = (gr < R_PERM);
  const float* gbase = G + (size_t)a_row * L_VAR + gl;
  const float* ybase = Yt + (size_t)gr * N_SAMP + b_col;

  float4 aR = aval ? *(const float4*)gbase : make_float4(0.f, 0.f, 0.f, 0.f);
  float4 bR = bval ? *(const float4*)ybase : make_float4(0.f, 0.f, 0.f, 0.f);

  float acc[4][4];
  #pragma unroll
  for (int u = 0; u < 4; ++u)
    #pragma unroll
    for (int v = 0; v < 4; ++v) acc[u][v] = 0.f;

  for (int i0 = 0; i0 < N_SAMP; i0 += 16) {
    *(float4*)&As[a_row][a_col] = aR;
    Bs[b_col + 0][b_row] = bR.x;
    Bs[b_col + 1][b_row] = bR.y;
    Bs[b_col + 2][b_row] = bR.z;
    Bs[b_col + 3][b_row] = bR.w;
    __syncthreads();
    int inext = i0 + 16;
    if (inext < N_SAMP) {
      aR = aval ? *(const float4*)(gbase + (size_t)inext * L_VAR) : make_float4(0.f, 0.f, 0.f, 0.f);
      bR = bval ? *(const float4*)(ybase + inext) : make_float4(0.f, 0.f, 0.f, 0.f);
    }
    #pragma unroll
    for (int k = 0; k < 16; ++k) {
      float4 av = *(const float4*)&As[k][tx * 4];
      float4 bv = *(const float4*)&Bs[k][ty * 4];
      float a4[4] = {av.x, av.y, av.z, av.w};
      float b4[4] = {bv.x, bv.y, bv.z, bv.w};
      #pragma unroll
      for (int u = 0; u < 4; ++u)
        #pragma unroll
        for (int v = 0; v < 4; ++v)
          acc[u][v] = fmaf(a4[u], b4[v], acc[u][v]);
    }
    __syncthreads();
  }
  #pragma unroll
  for (int v = 0; v < 4; ++v) {
    int rr = r0 + ty * 4 + v;
    float m = 0.f;
    #pragma unroll
    for (int u = 0; u < 4; ++u) {
      int ll = l0 + tx * 4 + u;
      if (ll < L_VAR) {
        float U = acc[u][v];
        float t = U * U / gg[ll];
        m = fmaxf(m, t);
      }
    }
    #pragma unroll
    for (int off = 8; off > 0; off >>= 1) m = fmaxf(m, __shfl_xor(m, off, 64));
    if (tx == 0 && rr < R_PERM) atomicMax(&s[rr], __float_as_uint(m));
  }
}

// ===== K5D (big): 32l x 64r tile, K-split 4 waves, full A+B double-buffer =====
// grid: 1280 blocks, XCD-swizzled so the 4 r-blocks sharing an A-tile land on
// the same XCD consecutively (xcd = bid & 7).
#define LSTR5 33
__global__ __launch_bounds__(256, 2) void k5d_mfma(
    const unsigned short* __restrict__ GTHI, const unsigned short* __restrict__ GTLO,
    const unsigned short* __restrict__ YHI, const unsigned short* __restrict__ YLO,
    const float* __restrict__ rgg, unsigned* __restrict__ s) {
  __shared__ float L[2][64 * LSTR5];
  int bid = blockIdx.x;
  int xcd = bid & 7, idx = bid >> 3;
  int rt = idx & 3, lg = idx >> 2;
  int lt = lg * 8 + xcd;
  if (lt >= LPAD / 32) return;
  int l0 = lt * 32, r0 = rt * 64;
  int tid = threadIdx.x;
  int w = tid >> 6, lam = tid & 63;
  int row16 = lam & 15, quad = lam >> 4;
  int kb = w * 512;

  const unsigned short* ah_p[2];
  const unsigned short* al_p[2];
  #pragma unroll
  for (int mt = 0; mt < 2; ++mt) {
    size_t base = (size_t)(l0 + mt * 16 + row16) * KPAD + kb + quad * 8;
    ah_p[mt] = GTHI + base;
    al_p[mt] = GTLO + base;
  }
  const unsigned short* bh_p[4];
  const unsigned short* bl_p[4];
  #pragma unroll
  for (int nt = 0; nt < 4; ++nt) {
    size_t base = (size_t)(r0 + nt * 16 + row16) * KPAD + kb + quad * 8;
    bh_p[nt] = YHI + base;
    bl_p[nt] = YLO + base;
  }

  float4v acc[2][4];
  #pragma unroll
  for (int mt = 0; mt < 2; ++mt)
    #pragma unroll
    for (int nt = 0; nt < 4; ++nt)
      acc[mt][nt] = (float4v){0.f, 0.f, 0.f, 0.f};

  short8v ah[2], al[2], bh[4], bl[4];
  #pragma unroll
  for (int mt = 0; mt < 2; ++mt) {
    ah[mt] = *(const short8v*)(ah_p[mt]);
    al[mt] = *(const short8v*)(al_p[mt]);
  }
  #pragma unroll
  for (int nt = 0; nt < 4; ++nt) {
    bh[nt] = *(const short8v*)(bh_p[nt]);
    bl[nt] = *(const short8v*)(bl_p[nt]);
  }

  #pragma unroll 1
  for (int step = 0; step < 16; ++step) {
    short8v nah[2], nal[2], nbh[4], nbl[4];
    bool more = (step < 15);
    if (more) {
      int ko = (step + 1) * 32;
      #pragma unroll
      for (int mt = 0; mt < 2; ++mt) {
        nah[mt] = *(const short8v*)(ah_p[mt] + ko);
        nal[mt] = *(const short8v*)(al_p[mt] + ko);
      }
      #pragma unroll
      for (int nt = 0; nt < 4; ++nt) {
        nbh[nt] = *(const short8v*)(bh_p[nt] + ko);
        nbl[nt] = *(const short8v*)(bl_p[nt] + ko);
      }
    }
    #pragma unroll
    for (int nt = 0; nt < 4; ++nt) {
      #pragma unroll
      for (int mt = 0; mt < 2; ++mt) {
        acc[mt][nt] = __builtin_amdgcn_mfma_f32_16x16x32_bf16(ah[mt], bh[nt], acc[mt][nt], 0, 0, 0);
        acc[mt][nt] = __builtin_amdgcn_mfma_f32_16x16x32_bf16(ah[mt], bl[nt], acc[mt][nt], 0, 0, 0);
        acc[mt][nt] = __builtin_amdgcn_mfma_f32_16x16x32_bf16(al[mt], bh[nt], acc[mt][nt], 0, 0, 0);
      }
    }
    if (more) {
      #pragma unroll
      for (int mt = 0; mt < 2; ++mt) { ah[mt] = nah[mt]; al[mt] = nal[mt]; }
      #pragma unroll
      for (int nt = 0; nt < 4; ++nt) { bh[nt] = nbh[nt]; bl[nt] = nbl[nt]; }
    }
  }

  // ---- cross-wave K reduction in LDS (2 rounds), epilogue on wave 0 ----
  if (w >= 2) {
    float* B = L[w - 2];
    #pragma unroll
    for (int mt = 0; mt < 2; ++mt)
      #pragma unroll
      for (int nt = 0; nt < 4; ++nt)
        #pragma unroll
        for (int q = 0; q < 4; ++q)
          B[(nt * 16 + row16) * LSTR5 + mt * 16 + quad * 4 + q] = acc[mt][nt][q];
  }
  __syncthreads();
  if (w < 2) {
    float* B = L[w];
    #pragma unroll
    for (int mt = 0; mt < 2; ++mt)
      #pragma unroll
      for (int nt = 0; nt < 4; ++nt)
        #pragma unroll
        for (int q = 0; q < 4; ++q)
          acc[mt][nt][q] += B[(nt * 16 + row16) * LSTR5 + mt * 16 + quad * 4 + q];
  }
  __syncthreads();
  if (w == 1) {
    float* B = L[0];
    #pragma unroll
    for (int mt = 0; mt < 2; ++mt)
      #pragma unroll
      for (int nt = 0; nt < 4; ++nt)
        #pragma unroll
        for (int q = 0; q < 4; ++q)
          B[(nt * 16 + row16) * LSTR5 + mt * 16 + quad * 4 + q] = acc[mt][nt][q];
  }
  __syncthreads();
  if (w == 0) {
    float* B = L[0];
    #pragma unroll
    for (int mt = 0; mt < 2; ++mt)
      #pragma unroll
      for (int nt = 0; nt < 4; ++nt)
        #pragma unroll
        for (int q = 0; q < 4; ++q)
          acc[mt][nt][q] += B[(nt * 16 + row16) * LSTR5 + mt * 16 + quad * 4 + q];
    float rl_[2][4];
    #pragma unroll
    for (int mt = 0; mt < 2; ++mt)
      #pragma unroll
      for (int q = 0; q < 4; ++q)
        rl_[mt][q] = rgg[l0 + mt * 16 + quad * 4 + q];
    #pragma unroll
    for (int nt = 0; nt < 4; ++nt) {
      float m = 0.f;
      #pragma unroll
      for (int mt = 0; mt < 2; ++mt)
        #pragma unroll
        for (int q = 0; q < 4; ++q) {
          float U = acc[mt][nt][q];
          m = fmaxf(m, U * U * rl_[mt][q]);
        }
      m = fmaxf(m, __shfl_xor(m, 16, 64));
      m = fmaxf(m, __shfl_xor(m, 32, 64));
      int r = r0 + nt * 16 + row16;
      if (quad == 0 && r < R_PERM) atomicMax(&s[r], __float_as_uint(m));
    }
  }
}

// ================= K6: TS^2 -> p -> MoM + lane-parallel Newton -> betainc =====
__global__ __launch_bounds__(256) void k6_final(
    const unsigned* __restrict__ sbits, const float* __restrict__ yty,
    const float* __restrict__ minp, float* __restrict__ out) {
  __shared__ double red[256];
  int tid = threadIdx.x;
  double p = 0.0, p2 = 0.0, lp = 0.0, l1p = 0.0;
  if (tid < R_PERM) {
    double t = (double)__uint_as_float(sbits[tid]);
    double Y = (double)yty[tid];
    double ts2 = DOF_D * t / (Y - t);
    double pp = erfc(sqrt(0.5 * ts2));
    p = pp; p2 = pp * pp; lp = log(pp); l1p = log1p(-pp);
  }
  double Sp  = breduce_add(p, red, tid);
  double Sp2 = breduce_add(p2, red, tid);
  double S1  = breduce_add(lp, red, tid);
  double S2  = breduce_add(l1p, red, tid);
  if (tid < 64) {
    const double nobs = (double)R_PERM;
    double mean = Sp / nobs;
    double var = Sp2 / nobs - mean * mean;
    double k = mean * (mean * (1.0 - mean) / var - 1.0);
    double n = k * (1.0 / mean - 1.0);
    double old_lik = 10000.0, diff = 1000.0;
    int iter = 0;
    int sel = tid % 3, grp = tid / 3;
    while (fabs(diff) > 1e-3 && iter <= 100) {
      double arg = (sel == 0) ? k : (sel == 1) ? n : (k + n);
      double v = 0.0;
      if (grp == 0) v = dg_trigamma(arg);
      else if (grp == 1) v = dg_tetragamma(arg);
      else if (grp == 2) v = dg_digamma(arg);
      double pg1k = __shfl(v, 0, 64), pg1n = __shfl(v, 1, 64), pg1kn = __shfl(v, 2, 64);
      double pg2k = __shfl(v, 3, 64), pg2n = __shfl(v, 4, 64), pg2kn = __shfl(v, 5, 64);
      double dgk  = __shfl(v, 6, 64), dgn  = __shfl(v, 7, 64), dgkn  = __shfl(v, 8, 64);
      double i_kn = -pg1kn, i_k = pg1k + i_kn, i_n = pg1n + i_kn;
      double A = -nobs * i_k, B = -nobs * i_kn, C = -nobs * i_n;
      double s0 = S1 - nobs * (dgk - dgkn);
      double s1 = S2 - nobs * (dgn - dgkn);
      double det = A * C - B * B;
      double d0 = (C * s0 - B * s1) / det;
      double d1 = (A * s1 - B * s0) / det;
      double i_kkn = pg1n * pg2kn;
      double g_k = -pg1n * pg2k + i_kkn + pg1kn * pg2k;
      double i_knn = i_kkn - pg1kn * pg2n;
      double i_nnk = pg1k * pg2kn;
      double i_nkk = i_nnk - pg1kn * pg2k;
      double g_n = -pg1k * pg2n + i_nnk + pg1kn * pg2n;
      double scale = -pg1k * pg1n + (pg1k + pg1n) * pg1kn;
      double f = 0.5 / scale;
      double adj0 = f * (g_k * d0 * d0 + 2.0 * i_kkn * d0 * d1 + i_knn * d1 * d1);
      double adj1 = f * (i_nkk * d0 * d0 + 2.0 * i_nnk * d0 * d1 + g_n * d1 * d1);
      double nk_ = k - d0 - 0.5 * adj0;
      double nn_ = n - d1 - 0.5 * adj1;
      double arg2 = (tid == 0) ? nk_ : (tid == 1) ? nn_ : (nk_ + nn_);
      double lg = (tid < 3) ? lgamma(arg2) : 0.0;
      double lgk = __shfl(lg, 0, 64), lgn = __shfl(lg, 1, 64), lgkn = __shfl(lg, 2, 64);
      double nl = (nk_ - 1.0) * S1 + (nn_ - 1.0) * S2 - nobs * (lgk + lgn - lgkn);
      diff = old_lik - nl;
      old_lik = nl; k = nk_; n = nn_; ++iter;
    }
    if (tid == 0) {
      double conv = (fabs(diff) < 1e-3 && iter <= 100) ? 1.0 : 0.0;
      double adj = betainc_d(k, n, (double)(*minp));
      out[0] = (float)adj;
      out[1] = (float)k;
      out[2] = (float)n;
      out[3] = (float)conv;
    }
  }
}

__global__ void k_err(float* out) {
  if (threadIdx.x < 4) out[threadIdx.x] = -12345.0f;
}

extern "C" void kernel_launch(void* const* d_in, const int* in_sizes, int n_in,
                              void* d_out, int out_size, void* d_ws, size_t ws_size,
                              hipStream_t stream) {
  const float* X     = (const float*)d_in[0];
  const float* y     = (const float*)d_in[1];
  const float* G     = (const float*)d_in[2];
  const float* obs_p = (const float*)d_in[3];
  const float* offs  = (const float*)d_in[4];
  const int*   seedp = (const int*)d_in[5];
  float* out = (float*)d_out;

  if (ws_size < WS_OLD) {
    k_err<<<1, 64, 0, stream>>>(out);
    return;
  }
  char* ws = (char*)d_ws;
  unsigned* pkeys = (unsigned*)(ws + OFF_PKEYS);
  double*   Mi    = (double*)(ws + OFF_MI);
  float*    minp  = (float*)(ws + OFF_MINP);
  float*    Xt    = (float*)(ws + OFF_XT);
  float*    XtGp  = (float*)(ws + OFF_XTGP);
  float*    GGp   = (float*)(ws + OFF_GGP);
  float*    gg    = (float*)(ws + OFF_GG);
  float*    yty   = (float*)(ws + OFF_YTY);
  unsigned* s     = (unsigned*)(ws + OFF_S);
  float*    Yt    = (float*)(ws + OFF_YT);

  bool big = (ws_size >= WS_BIG);
  float*          rgg   = big ? (float*)(ws + OFF_RGG) : nullptr;
  unsigned short* yhi   = big ? (unsigned short*)(ws + OFF_YHI) : nullptr;
  unsigned short* ylo   = big ? (unsigned short*)(ws + OFF_YLO) : nullptr;
  float*          XtGp2 = big ? (float*)(ws + OFF_XTGP2) : nullptr;
  float*          GGp2  = big ? (float*)(ws + OFF_GGP2) : nullptr;
  unsigned short* GTHI  = big ? (unsigned short*)(ws + OFF_GTHI) : nullptr;
  unsigned short* GTLO  = big ? (unsigned short*)(ws + OFF_GTLO) : nullptr;

  k1_setup<<<3, 256, 0, stream>>>(X, obs_p, Xt, Mi, minp);
  if (big) {
    kz_pad<<<RPAD - R_PERM, 256, 0, stream>>>(yhi, ylo);
    k2t_pass<<<dim3(158, 16), 256, 0, stream>>>(G, X, seedp, GTHI, GTLO, XtGp2, GGp2, pkeys);
    k3t_gg<<<40, 256, 0, stream>>>(XtGp2, GGp2, Mi, gg, rgg);
    // big path: skip fallback-Yt write (region overlaps YHI) -> pass nullptr
    k4_perm<<<R_PERM, 256, 0, stream>>>(y, offs, Xt, pkeys, Mi, nullptr, yty, s, yhi, ylo);
    k5d_mfma<<<1280, 256, 0, stream>>>(GTHI, GTLO, yhi, ylo, rgg, s);
  } else {
    k2_xtg<<<dim3(41, 5), 256, 0, stream>>>(G, X, seedp, XtGp, GGp, pkeys);
    k3_gg<<<40, 256, 0, stream>>>(XtGp, GGp, Mi, gg);
    k4_perm<<<R_PERM, 256, 0, stream>>>(y, offs, Xt, pkeys, Mi, Yt, yty, s, nullptr, nullptr);
    k5_gemm<<<dim3(157, 4), 256, 0, stream>>>(G, Yt, gg, s);
  }
  k6_final<<<1, 256, 0, stream>>>(s, yty, minp, out);
}

// Round 6
// 429.958 us; speedup vs baseline: 1.1289x; 1.1289x over previous
//
#include <hip/hip_runtime.h>
#include <stdint.h>

// PRNG variant: 1 = jax_threefry_partitionable=True (JAX >= 0.4.36 default)
#ifndef JAX_THREEFRY_PARTITIONABLE
#define JAX_THREEFRY_PARTITIONABLE 1
#endif

#define N_SAMP 2000
#define L_VAR  10000
#define R_PERM 200
#define DOF_D  1989.0   // N - K - 1

#define KPAD   2048     // padded K (samples) for MFMA path
#define LPAD   10048    // padded L (157*64)
#define RPAD   256      // padded R

// ---------------- workspace layout (bytes) ----------------
// ---- fallback region (layout identical to round-2 kernel) ----
#define OFF_PKEYS  0UL
#define OFF_MI     1664UL
#define OFF_MINP   2464UL
#define OFF_XT     2560UL
#define OFF_XTGP   82560UL     // fallback only
#define OFF_GGP    2082560UL   // fallback only
#define OFF_GG     2282560UL
#define OFF_YTY    2322560UL
#define OFF_S      2323392UL
#define OFF_YT     2324224UL   // fallback only (big path overlaps with YHI)
#define WS_OLD     3924224UL
// ---- big-ws (MFMA) region; overlaps fallback-only scratch ----
#define OFF_GGP2   82560UL     // float[16][10048] = 643,072 (over fallback XTGP)
#define OFF_RGG    725632UL    // float[10048]
#define OFF_YHI    2324224UL   // u16[256][2048] = 1,048,576 (over fallback YT)
#define OFF_XTGP2  3924224UL   // float[16][10][10048] = 6,430,720
#define OFF_YLO    10354944UL  // u16[256][2048]
#define OFF_GTHI   11403520UL  // u16[10048][2048] = 41,156,608
#define OFF_GTLO   52560128UL  // u16[10048][2048] -> ends 93,716,736
#define WS_BIG     95186432UL  // known good (rounds 3-5 ran big path)

typedef __attribute__((ext_vector_type(8))) short short8v;   // 8 bf16
typedef __attribute__((ext_vector_type(4))) float float4v;   // MFMA acc

// ---------------- threefry2x32, JAX-exact ----------------
__device__ __forceinline__ uint32_t rotl32(uint32_t v, int d) {
  return (v << d) | (v >> (32 - d));
}
__device__ __forceinline__ uint2 tf2(uint32_t k0, uint32_t k1, uint32_t x0, uint32_t x1) {
  uint32_t ks2 = k0 ^ k1 ^ 0x1BD11BDAu;
  x0 += k0; x1 += k1;
#define TF4(a,b,c,d) \
  x0 += x1; x1 = rotl32(x1,a); x1 ^= x0; \
  x0 += x1; x1 = rotl32(x1,b); x1 ^= x0; \
  x0 += x1; x1 = rotl32(x1,c); x1 ^= x0; \
  x0 += x1; x1 = rotl32(x1,d); x1 ^= x0;
  TF4(13,15,26,6)  x0 += k1;  x1 += ks2 + 1u;
  TF4(17,29,16,24) x0 += ks2; x1 += k0 + 2u;
  TF4(13,15,26,6)  x0 += k0;  x1 += k1 + 3u;
  TF4(17,29,16,24) x0 += k1;  x1 += ks2 + 4u;
  TF4(13,15,26,6)  x0 += ks2; x1 += k0 + 5u;
#undef TF4
  return make_uint2(x0, x1);
}

// single-thread fallback key chain
__device__ __forceinline__ void gen_pkeys(const int* seedp, unsigned* pkeys) {
  uint32_t khi = 0u, klo = (uint32_t)(*seedp);
  for (int r = 0; r < R_PERM; ++r) {
#if JAX_THREEFRY_PARTITIONABLE
    uint2 pk = tf2(khi, klo, 0u, 1u);
    uint2 nk = tf2(khi, klo, 0u, 0u);
#else
    uint2 t0 = tf2(khi, klo, 0u, 2u);
    uint2 t1 = tf2(khi, klo, 1u, 3u);
    uint2 nk = make_uint2(t0.x, t1.x);
    uint2 pk = make_uint2(t0.y, t1.y);
#endif
    pkeys[2 * r] = pk.x; pkeys[2 * r + 1] = pk.y;
    khi = nk.x; klo = nk.y;
  }
}

// ---------------- block reduce (256 threads, for k6) ----------------
__device__ __forceinline__ double breduce_add(double v, double* red, int tid) {
  red[tid] = v; __syncthreads();
  for (int off = 128; off > 0; off >>= 1) {
    if (tid < off) red[tid] += red[tid + off];
    __syncthreads();
  }
  double r = red[0]; __syncthreads();
  return r;
}

// wave-shuffle + 16-slot LDS reduce (for 1024-thread k4)
__device__ __forceinline__ double breduce_w(double v, double* red16, int tid, int nw) {
  #pragma unroll
  for (int off = 32; off > 0; off >>= 1) v += __shfl_xor(v, off, 64);
  if ((tid & 63) == 0) red16[tid >> 6] = v;
  __syncthreads();
  double r = 0.0;
  for (int i = 0; i < nw; ++i) r += red16[i];
  __syncthreads();
  return r;
}

// ---------------- special functions (double) ----------------
__device__ double dg_digamma(double x) {
  if (!(x > 0.0)) return __builtin_nan("");
  double r = 0.0;
  while (x < 8.0) { r -= 1.0 / x; x += 1.0; }
  double t = 1.0 / x, t2 = t * t;
  double ser = t2 * (1.0/12.0 - t2*(1.0/120.0 - t2*(1.0/252.0 - t2*(1.0/240.0 - t2*(1.0/132.0)))));
  return r + log(x) - 0.5 * t - ser;
}
__device__ double dg_trigamma(double x) {
  if (!(x > 0.0)) return __builtin_nan("");
  double r = 0.0;
  while (x < 8.0) { r += 1.0 / (x * x); x += 1.0; }
  double t = 1.0 / x, t2 = t * t;
  double P = 1.0/6.0 - t2*(1.0/30.0 - t2*(1.0/42.0 - t2*(1.0/30.0 - t2*(5.0/66.0))));
  return r + t + 0.5 * t2 + t * t2 * P;
}
__device__ double dg_tetragamma(double x) {
  if (!(x > 0.0)) return __builtin_nan("");
  double r = 0.0;
  while (x < 8.0) { r -= 2.0 / (x * x * x); x += 1.0; }
  double t = 1.0 / x, t2 = t * t;
  double Q = 1.0 + t + 0.5*t2 - t2*t2*(1.0/6.0 - t2*(1.0/6.0 - t2*(3.0/10.0)));
  return r - t2 * Q;
}
__device__ double betacf_d(double a, double b, double x) {
  const double FPMIN = 1e-300, EPS = 3e-16;
  double qab = a + b, qap = a + 1.0, qam = a - 1.0;
  double c = 1.0, d = 1.0 - qab * x / qap;
  if (fabs(d) < FPMIN) d = FPMIN;
  d = 1.0 / d; double h = d;
  for (int m = 1; m <= 300; ++m) {
    int m2 = 2 * m;
    double aa = m * (b - m) * x / ((qam + m2) * (a + m2));
    d = 1.0 + aa * d; if (fabs(d) < FPMIN) d = FPMIN;
    c = 1.0 + aa / c; if (fabs(c) < FPMIN) c = FPMIN;
    d = 1.0 / d; double del = d * c; h *= del;
    aa = -(a + m) * (qab + m) * x / ((a + m2) * (qap + m2));
    d = 1.0 + aa * d; if (fabs(d) < FPMIN) d = FPMIN;
    c = 1.0 + aa / c; if (fabs(c) < FPMIN) c = FPMIN;
    d = 1.0 / d; del = d * c; h *= del;
    if (fabs(del - 1.0) < EPS) break;
  }
  return h;
}
__device__ double betainc_d(double a, double b, double x) {
  if (!(x > 0.0)) return 0.0;
  if (x >= 1.0) return 1.0;
  double lnbt = lgamma(a + b) - lgamma(a) - lgamma(b) + a * log(x) + b * log1p(-x);
  double bt = exp(lnbt);
  if (x < (a + 1.0) / (a + b + 2.0)) return bt * betacf_d(a, b, x) / a;
  else return 1.0 - bt * betacf_d(b, a, 1.0 - x) / b;
}

// ---------------- bitonic sort of 2048 u64 (stable u32 sort), stride-generic --
__device__ __forceinline__ void bitonic2048(unsigned long long* arr, int tid, int nthr) {
  for (int size = 2; size <= 2048; size <<= 1) {
    for (int stride = size >> 1; stride > 0; stride >>= 1) {
      __syncthreads();
      for (int p = tid; p < 1024; p += nthr) {
        int i = 2 * p - (p & (stride - 1));
        int j = i + stride;
        bool up = ((i & size) == 0);
        unsigned long long a = arr[i], b = arr[j];
        bool sw = up ? (a > b) : (a < b);
        if (sw) { arr[i] = b; arr[j] = a; }
      }
    }
  }
  __syncthreads();
}

__device__ __forceinline__ void fill_keys(unsigned long long* arr, uint32_t kx, uint32_t ky,
                                          int tid, int nthr) {
#if JAX_THREEFRY_PARTITIONABLE
  for (int i = tid; i < 2048; i += nthr) {
    if (i < 2000) {
      uint2 o = tf2(kx, ky, 0u, (uint32_t)i);
      uint32_t bits = o.x ^ o.y;
      arr[i] = (((unsigned long long)bits) << 11) | (unsigned long long)i;
    } else {
      arr[i] = ~0ull;
    }
  }
#else
  for (int j = tid; j < 1024; j += nthr) {
    if (j < 1000) {
      uint2 o = tf2(kx, ky, (uint32_t)j, (uint32_t)(1000 + j));
      arr[j]        = (((unsigned long long)o.x) << 11) | (unsigned long long)j;
      arr[1000 + j] = (((unsigned long long)o.y) << 11) | (unsigned long long)(1000 + j);
    }
  }
  for (int i = 2000 + tid; i < 2048; i += nthr) arr[i] = ~0ull;
#endif
}

__device__ __forceinline__ void tri_ab(int q, int& a, int& b) {
  int aa = 0, rem = q;
  while (rem >= 10 - aa) { rem -= 10 - aa; ++aa; }
  a = aa; b = aa + rem;
}

// split fp32 -> bf16 hi + bf16 lo (truncation split)
__device__ __forceinline__ void bf16split(float f, unsigned short& h, unsigned short& l) {
  unsigned u = __float_as_uint(f);
  h = (unsigned short)(u >> 16);
  float rem = f - __uint_as_float(u & 0xFFFF0000u);
  l = (unsigned short)(__float_as_uint(rem) >> 16);
}

// ====== K1: XtX inverse (LDS GJ), min(obs_p), X^T, bf16-Y pad-zero ============
__global__ __launch_bounds__(256) void k1_setup(
    const float* __restrict__ X, const float* __restrict__ obs_p,
    float* __restrict__ Xt, double* __restrict__ Mi, float* __restrict__ minp,
    unsigned short* __restrict__ yhi, unsigned short* __restrict__ ylo) {
  int tid = threadIdx.x;
  if (blockIdx.x == 0) {
    __shared__ double xtx_sh[55];
    __shared__ double A[10][21];
    __shared__ int piv_sh;
    __shared__ double pv_sh;
    int wave = tid >> 6, lane = tid & 63;
    for (int q = wave; q < 55; q += 4) {
      int a, b; tri_ab(q, a, b);
      double acc = 0.0;
      for (int i = lane; i < N_SAMP; i += 64)
        acc += (double)X[i * 10 + a] * (double)X[i * 10 + b];
      for (int off = 32; off > 0; off >>= 1) acc += __shfl_xor(acc, off, 64);
      if (lane == 0) xtx_sh[q] = acc;
    }
    __syncthreads();
    if (tid < 200) {
      int r = tid / 20, j = tid % 20;
      double v;
      if (j < 10) {
        int a = r < j ? r : j;
        int b = r < j ? j : r;
        int q = 10 * a - a * (a - 1) / 2 + (b - a);
        v = xtx_sh[q];
      } else {
        v = (j - 10 == r) ? 1.0 : 0.0;
      }
      A[r][j] = v;
    }
    __syncthreads();
    int r_ = tid / 20, j_ = tid % 20;
    bool in200 = (tid < 200);
    for (int c = 0; c < 10; ++c) {
      if (tid == 0) {
        int piv = c; double best = fabs(A[c][c]);
        for (int r2 = c + 1; r2 < 10; ++r2)
          if (fabs(A[r2][c]) > best) { best = fabs(A[r2][c]); piv = r2; }
        piv_sh = piv;
      }
      __syncthreads();
      int piv = piv_sh;
      if (piv != c && tid < 20) {
        double t = A[c][tid]; A[c][tid] = A[piv][tid]; A[piv][tid] = t;
      }
      __syncthreads();
      if (tid == 0) pv_sh = A[c][c];
      __syncthreads();
      if (tid < 20) A[c][tid] *= (1.0 / pv_sh);
      __syncthreads();
      double f = 0.0, acj = 0.0;
      bool act = in200 && (r_ != c);
      if (act) { f = A[r_][c]; acj = A[c][j_]; }
      __syncthreads();
      if (act) A[r_][j_] -= f * acj;
      __syncthreads();
    }
    if (tid < 100) Mi[tid] = A[tid / 10][10 + (tid % 10)];
  } else if (blockIdx.x == 1) {
    __shared__ float redf[256];
    float m = 1e30f;
    for (int i = tid; i < L_VAR; i += 256) m = fminf(m, obs_p[i]);
    redf[tid] = m; __syncthreads();
    for (int off = 128; off > 0; off >>= 1) {
      if (tid < off) redf[tid] = fminf(redf[tid], redf[tid + off]);
      __syncthreads();
    }
    if (tid == 0) *minp = redf[0];
  } else if (blockIdx.x == 2) {
    for (int idx = tid; idx < 10 * N_SAMP; idx += 256) {
      int k = idx / N_SAMP, i = idx - k * N_SAMP;
      Xt[idx] = X[i * 10 + k];
    }
  } else {
    // blocks 3..58: zero bf16 Yt pad rows 200..255 (big path only)
    if (yhi) {
      int row = R_PERM + (blockIdx.x - 3);
      size_t base = (size_t)row * KPAD;
      for (int i = tid; i < KPAD; i += 256) {
        yhi[base + i] = 0;
        ylo[base + i] = 0;
      }
    }
  }
}

// ================= K2 (fallback): XtG/GG partials + key chain =================
__global__ __launch_bounds__(256) void k2_xtg(
    const float* __restrict__ G, const float* __restrict__ X,
    const int* __restrict__ seedp, float* __restrict__ XtGp,
    float* __restrict__ GGp, unsigned* __restrict__ pkeys) {
  if (blockIdx.x == 40) {
    if (blockIdx.y == 0 && threadIdx.x == 0) gen_pkeys(seedp, pkeys);
    return;
  }
  int l = blockIdx.x * 256 + threadIdx.x;
  bool valid = (l < L_VAR);
  int i0 = blockIdx.y * 400;
  float acc[10];
  #pragma unroll
  for (int k = 0; k < 10; ++k) acc[k] = 0.f;
  float g2 = 0.f;
  for (int i = i0; i < i0 + 400; ++i) {
    float g = valid ? G[(size_t)i * L_VAR + l] : 0.f;
    #pragma unroll
    for (int k = 0; k < 10; ++k) acc[k] = fmaf(g, X[i * 10 + k], acc[k]);
    g2 = fmaf(g, g, g2);
  }
  if (valid) {
    int part = blockIdx.y;
    #pragma unroll
    for (int k = 0; k < 10; ++k)
      XtGp[((size_t)part * 10 + k) * L_VAR + l] = acc[k];
    GGp[(size_t)part * L_VAR + l] = g2;
  }
}

// ===== K2T (big): G pass -> G^T bf16 hi/lo + XtG/GG partials + key chain =====
__global__ __launch_bounds__(256) void k2t_pass(
    const float* __restrict__ G, const float* __restrict__ X,
    const int* __restrict__ seedp,
    unsigned short* __restrict__ GTHI, unsigned short* __restrict__ GTLO,
    float* __restrict__ XtGp2, float* __restrict__ GGp2,
    unsigned* __restrict__ pkeys) {
  if (blockIdx.x == 157) {
    // 2-lane parallel key chain: lane 0 computes next-key, lane 1 computes perm-key
    if (blockIdx.y == 0 && threadIdx.x < 2) {
      int t = threadIdx.x;
      uint32_t khi = 0u, klo = (uint32_t)(*seedp);
#if JAX_THREEFRY_PARTITIONABLE
      for (int r = 0; r < R_PERM; ++r) {
        uint2 res = tf2(khi, klo, 0u, (uint32_t)t);   // t=0 -> nk, t=1 -> pk
        if (t == 1) { pkeys[2 * r] = res.x; pkeys[2 * r + 1] = res.y; }
        khi = __shfl(res.x, 0, 64);
        klo = __shfl(res.y, 0, 64);
      }
#else
      if (t == 0) gen_pkeys(seedp, pkeys);
#endif
    }
    return;
  }
  __shared__ float T[128][69];
  __shared__ float Xsh[128][10];
  int tid = threadIdx.x;
  int l0 = blockIdx.x * 64, i0 = blockIdx.y * 128;
  for (int it = 0; it < 8; ++it) {
    int fi = it * 256 + tid;
    int row = fi >> 4, c4 = (fi & 15) * 4;
    int i = i0 + row, l = l0 + c4;
    float4 v = make_float4(0.f, 0.f, 0.f, 0.f);
    if (i < N_SAMP && l + 3 < L_VAR) v = *(const float4*)(G + (size_t)i * L_VAR + l);
    T[row][c4 + 0] = v.x; T[row][c4 + 1] = v.y; T[row][c4 + 2] = v.z; T[row][c4 + 3] = v.w;
  }
  for (int q = 0; q < 5; ++q) {
    int idx = q * 256 + tid;
    if (idx < 1280) {
      int row = idx / 10, k = idx - row * 10;
      int i = i0 + row;
      Xsh[row][k] = (i < N_SAMP) ? X[i * 10 + k] : 0.f;
    }
  }
  __syncthreads();
  {
    int w = tid >> 6, lam = tid & 63;
    int half = lam >> 5, i4 = (lam & 31) * 4;
    for (int g = 0; g < 8; ++g) {
      int lloc = g * 8 + w * 2 + half;
      float fv[4];
      fv[0] = T[i4 + 0][lloc]; fv[1] = T[i4 + 1][lloc];
      fv[2] = T[i4 + 2][lloc]; fv[3] = T[i4 + 3][lloc];
      ushort4 hv, lv;
      bf16split(fv[0], hv.x, lv.x);
      bf16split(fv[1], hv.y, lv.y);
      bf16split(fv[2], hv.z, lv.z);
      bf16split(fv[3], hv.w, lv.w);
      size_t idx = (size_t)(l0 + lloc) * KPAD + i0 + i4;
      *(ushort4*)(GTHI + idx) = hv;
      *(ushort4*)(GTLO + idx) = lv;
    }
  }
  int lc = tid & 63, iq = tid >> 6;
  float accx[10];
  #pragma unroll
  for (int k = 0; k < 10; ++k) accx[k] = 0.f;
  float g2 = 0.f;
  for (int j = 0; j < 32; ++j) {
    int i = iq * 32 + j;
    float tv = T[i][lc];
    g2 = fmaf(tv, tv, g2);
    #pragma unroll
    for (int k = 0; k < 10; ++k) accx[k] = fmaf(tv, Xsh[i][k], accx[k]);
  }
  __syncthreads();
  float* scr = &T[0][0];
  #pragma unroll
  for (int k = 0; k < 10; ++k) scr[(iq * 64 + lc) * 10 + k] = accx[k];
  scr[2560 + iq * 64 + lc] = g2;
  __syncthreads();
  for (int idx = tid; idx < 640; idx += 256) {
    int l = idx / 10, k = idx - l * 10;
    float t = scr[(0 * 64 + l) * 10 + k] + scr[(1 * 64 + l) * 10 + k]
            + scr[(2 * 64 + l) * 10 + k] + scr[(3 * 64 + l) * 10 + k];
    XtGp2[((size_t)blockIdx.y * 10 + k) * LPAD + l0 + l] = t;
  }
  if (tid < 64) {
    float s4 = scr[2560 + tid] + scr[2560 + 64 + tid] + scr[2560 + 128 + tid] + scr[2560 + 192 + tid];
    GGp2[(size_t)blockIdx.y * LPAD + l0 + tid] = s4;
  }
}

// ================= K3 (fallback) ==============================================
__global__ __launch_bounds__(256) void k3_gg(
    const float* __restrict__ XtGp, const float* __restrict__ GGp,
    const double* __restrict__ Mi, float* __restrict__ gg) {
  int l = blockIdx.x * 256 + threadIdx.x;
  if (l >= L_VAR) return;
  double t[10]; double g2 = 0.0;
  #pragma unroll
  for (int k = 0; k < 10; ++k) t[k] = 0.0;
  for (int part = 0; part < 5; ++part) {
    #pragma unroll
    for (int k = 0; k < 10; ++k)
      t[k] += (double)XtGp[((size_t)part * 10 + k) * L_VAR + l];
    g2 += (double)GGp[(size_t)part * L_VAR + l];
  }
  double corr = 0.0;
  #pragma unroll
  for (int k = 0; k < 10; ++k) {
    double a = 0.0;
    #pragma unroll
    for (int j = 0; j < 10; ++j) a += Mi[k * 10 + j] * t[j];
    corr += a * t[k];
  }
  gg[l] = (float)(g2 - corr);
}

// ================= K3T (big): gg + rgg from 16 partials =======================
__global__ __launch_bounds__(256) void k3t_gg(
    const float* __restrict__ XtGp2, const float* __restrict__ GGp2,
    const double* __restrict__ Mi, float* __restrict__ gg, float* __restrict__ rgg) {
  int l = blockIdx.x * 256 + threadIdx.x;
  if (l >= LPAD) return;
  double t[10]; double g2 = 0.0;
  #pragma unroll
  for (int k = 0; k < 10; ++k) t[k] = 0.0;
  for (int part = 0; part < 16; ++part) {
    #pragma unroll
    for (int k = 0; k < 10; ++k)
      t[k] += (double)XtGp2[((size_t)part * 10 + k) * LPAD + l];
    g2 += (double)GGp2[(size_t)part * LPAD + l];
  }
  double corr = 0.0;
  #pragma unroll
  for (int k = 0; k < 10; ++k) {
    double a = 0.0;
    #pragma unroll
    for (int j = 0; j < 10; ++j) a += Mi[k * 10 + j] * t[j];
    corr += a * t[k];
  }
  double v = g2 - corr;
  if (l < L_VAR) {
    gg[l] = (float)v;
    rgg[l] = (v > 0.0) ? (float)(1.0 / v) : 0.f;
  } else {
    rgg[l] = 0.f;
  }
}

// ======= K4 (1024 thr): per-permutation shuffle + residualized Yt =============
__global__ __launch_bounds__(1024) void k4_perm(
    const float* __restrict__ y, const float* __restrict__ offs,
    const float* __restrict__ Xt, const unsigned* __restrict__ pkeys,
    const double* __restrict__ Mi, float* __restrict__ Yt,
    float* __restrict__ yty, unsigned* __restrict__ s,
    unsigned short* __restrict__ yhi, unsigned short* __restrict__ ylo) {
  __shared__ unsigned long long arr[2048];
  __shared__ unsigned short sig1[2048];
  __shared__ float yp[2000];
  __shared__ double red16[16];
  __shared__ double mvd[10];
  __shared__ unsigned ksh[4];
  const int NT = 1024;
  int r = blockIdx.x, tid = threadIdx.x;

  if (tid == 0) {
    uint32_t phi = pkeys[2 * r], plo = pkeys[2 * r + 1];
#if JAX_THREEFRY_PARTITIONABLE
    uint2 sub1 = tf2(phi, plo, 0u, 1u);
    uint2 key1 = tf2(phi, plo, 0u, 0u);
    uint2 sub2 = tf2(key1.x, key1.y, 0u, 1u);
#else
    uint2 a0 = tf2(phi, plo, 0u, 2u), a1 = tf2(phi, plo, 1u, 3u);
    uint2 key1 = make_uint2(a0.x, a1.x);
    uint2 sub1 = make_uint2(a0.y, a1.y);
    uint2 b0 = tf2(key1.x, key1.y, 0u, 2u), b1 = tf2(key1.x, key1.y, 1u, 3u);
    uint2 sub2 = make_uint2(b0.y, b1.y);
#endif
    ksh[0] = sub1.x; ksh[1] = sub1.y; ksh[2] = sub2.x; ksh[3] = sub2.y;
  }
  __syncthreads();
  uint32_t s1x = ksh[0], s1y = ksh[1], s2x = ksh[2], s2y = ksh[3];

  fill_keys(arr, s1x, s1y, tid, NT);
  bitonic2048(arr, tid, NT);
  for (int i = tid; i < 2048; i += NT) sig1[i] = (unsigned short)(arr[i] & 2047u);
  __syncthreads();
  fill_keys(arr, s2x, s2y, tid, NT);
  bitonic2048(arr, tid, NT);
  for (int i = tid; i < N_SAMP; i += NT) {
    int s2i = (int)(arr[i] & 2047u);
    int fin = (int)sig1[s2i];
    yp[i] = y[fin] - offs[i];
  }
  __syncthreads();

  double wloc[10];
  #pragma unroll
  for (int k = 0; k < 10; ++k) wloc[k] = 0.0;
  for (int i = tid; i < N_SAMP; i += NT) {
    double v = (double)yp[i];
    #pragma unroll
    for (int k = 0; k < 10; ++k) wloc[k] += (double)Xt[k * N_SAMP + i] * v;
  }
  double wfull[10];
  for (int k = 0; k < 10; ++k) wfull[k] = breduce_w(wloc[k], red16, tid, 16);
  if (tid == 0) {
    #pragma unroll
    for (int j = 0; j < 10; ++j) {
      double m = 0.0;
      #pragma unroll
      for (int k = 0; k < 10; ++k) m += Mi[j * 10 + k] * wfull[k];
      mvd[j] = m;
    }
  }
  __syncthreads();

  double acc = 0.0;
  for (int i = tid; i < N_SAMP; i += NT) {
    double d = (double)yp[i];
    #pragma unroll
    for (int k = 0; k < 10; ++k) d -= (double)Xt[k * N_SAMP + i] * mvd[k];
    float v = (float)d;
    if (Yt) Yt[(size_t)r * N_SAMP + i] = v;
    yp[i] = v;
    acc += (double)v * (double)v;
  }
  double tot = breduce_w(acc, red16, tid, 16);
  if (tid == 0) { yty[r] = (float)tot; s[r] = 0u; }

  __syncthreads();
  if (yhi) {
    for (int i = tid; i < KPAD; i += NT) {
      float v = (i < N_SAMP) ? yp[i] : 0.f;
      unsigned short h, l;
      bf16split(v, h, l);
      yhi[(size_t)r * KPAD + i] = h;
      ylo[(size_t)r * KPAD + i] = l;
    }
  }
}

// ================= K5 (fallback): fp32 VALU GEMM ==============================
__global__ __launch_bounds__(256) void k5_gemm(
    const float* __restrict__ G, const float* __restrict__ Yt,
    const float* __restrict__ gg, unsigned* __restrict__ s) {
  __shared__ float As[16][64];
  __shared__ float Bs[16][68];
  int tid = threadIdx.x;
  int tx = tid & 15, ty = tid >> 4;
  int l0 = blockIdx.x * 64, r0 = blockIdx.y * 64;
  int a_row = tid >> 4;
  int a_col = (tid & 15) * 4;
  int b_row = tid >> 2;
  int b_col = (tid & 3) * 4;
  int gl = l0 + a_col;
  bool aval = (gl < L_VAR);
  int gr = r0 + b_row;
  bool bval = (gr < R_PERM);
  const float* gbase = G + (size_t)a_row * L_VAR + gl;
  const float* ybase = Yt + (size_t)gr * N_SAMP + b_col;

  float4 aR = aval ? *(const float4*)gbase : make_float4(0.f, 0.f, 0.f, 0.f);
  float4 bR = bval ? *(const float4*)ybase : make_float4(0.f, 0.f, 0.f, 0.f);

  float acc[4][4];
  #pragma unroll
  for (int u = 0; u < 4; ++u)
    #pragma unroll
    for (int v = 0; v < 4; ++v) acc[u][v] = 0.f;

  for (int i0 = 0; i0 < N_SAMP; i0 += 16) {
    *(float4*)&As[a_row][a_col] = aR;
    Bs[b_col + 0][b_row] = bR.x;
    Bs[b_col + 1][b_row] = bR.y;
    Bs[b_col + 2][b_row] = bR.z;
    Bs[b_col + 3][b_row] = bR.w;
    __syncthreads();
    int inext = i0 + 16;
    if (inext < N_SAMP) {
      aR = aval ? *(const float4*)(gbase + (size_t)inext * L_VAR) : make_float4(0.f, 0.f, 0.f, 0.f);
      bR = bval ? *(const float4*)(ybase + inext) : make_float4(0.f, 0.f, 0.f, 0.f);
    }
    #pragma unroll
    for (int k = 0; k < 16; ++k) {
      float4 av = *(const float4*)&As[k][tx * 4];
      float4 bv = *(const float4*)&Bs[k][ty * 4];
      float a4[4] = {av.x, av.y, av.z, av.w};
      float b4[4] = {bv.x, bv.y, bv.z, bv.w};
      #pragma unroll
      for (int u = 0; u < 4; ++u)
        #pragma unroll
        for (int v = 0; v < 4; ++v)
          acc[u][v] = fmaf(a4[u], b4[v], acc[u][v]);
    }
    __syncthreads();
  }
  #pragma unroll
  for (int v = 0; v < 4; ++v) {
    int rr = r0 + ty * 4 + v;
    float m = 0.f;
    #pragma unroll
    for (int u = 0; u < 4; ++u) {
      int ll = l0 + tx * 4 + u;
      if (ll < L_VAR) {
        float U = acc[u][v];
        float t = U * U / gg[ll];
        m = fmaxf(m, t);
      }
    }
    #pragma unroll
    for (int off = 8; off > 0; off >>= 1) m = fmaxf(m, __shfl_xor(m, off, 64));
    if (tx == 0 && rr < R_PERM) atomicMax(&s[rr], __float_as_uint(m));
  }
}

// ===== K5F (big): m97-style async-LDS-staged bf16x3 MFMA GEMM =================
// 157 blocks x 256 thr (4 waves). Block C-tile = 64 l x 256 r, full K.
// Wave w computes 64l x 64r (r-range w*64), mt=4, nt=4.
// LDS double-buffered: Ah/Al 64x32, Bh/Bl 256x32 -> 80 KB total.
// Staging via __builtin_amdgcn_global_load_lds width=16: 40 x 1KB DMA per step,
// wave w stages chunks [w*10, w*10+10).
__device__ __forceinline__ void k5f_stage(
    int w, int lane, int kb, int l0,
    const unsigned short* __restrict__ GTHI, const unsigned short* __restrict__ GTLO,
    const unsigned short* __restrict__ YHI, const unsigned short* __restrict__ YLO,
    unsigned short* Ah, unsigned short* Al, unsigned short* Bh, unsigned short* Bl) {
  int sub = lane >> 2, kq = lane & 3;
  #pragma unroll
  for (int j = 0; j < 10; ++j) {
    int c = w * 10 + j;
    const unsigned short* src;
    unsigned short* dst;
    if (c < 4) {
      src = GTHI + (size_t)(l0 + c * 16 + sub) * KPAD + kb + kq * 8;
      dst = Ah + c * 512 + lane * 8;
    } else if (c < 8) {
      src = GTLO + (size_t)(l0 + (c - 4) * 16 + sub) * KPAD + kb + kq * 8;
      dst = Al + (c - 4) * 512 + lane * 8;
    } else if (c < 24) {
      src = YHI + (size_t)((c - 8) * 16 + sub) * KPAD + kb + kq * 8;
      dst = Bh + (c - 8) * 512 + lane * 8;
    } else {
      src = YLO + (size_t)((c - 24) * 16 + sub) * KPAD + kb + kq * 8;
      dst = Bl + (c - 24) * 512 + lane * 8;
    }
    __builtin_amdgcn_global_load_lds(
        (const __attribute__((address_space(1))) unsigned int*)(const void*)src,
        (__attribute__((address_space(3))) unsigned int*)(void*)dst, 16, 0, 0);
  }
}

__global__ __launch_bounds__(256) void k5f_mfma(
    const unsigned short* __restrict__ GTHI, const unsigned short* __restrict__ GTLO,
    const unsigned short* __restrict__ YHI, const unsigned short* __restrict__ YLO,
    const float* __restrict__ rgg, unsigned* __restrict__ s) {
  __shared__ unsigned short Ah[2][64 * 32];
  __shared__ unsigned short Al[2][64 * 32];
  __shared__ unsigned short Bh[2][256 * 32];
  __shared__ unsigned short Bl[2][256 * 32];
  int tid = threadIdx.x;
  int w = tid >> 6, lane = tid & 63;
  int row16 = lane & 15, quad = lane >> 4;
  int l0 = blockIdx.x * 64;

  float4v acc[4][4];
  #pragma unroll
  for (int mt = 0; mt < 4; ++mt)
    #pragma unroll
    for (int nt = 0; nt < 4; ++nt)
      acc[mt][nt] = (float4v){0.f, 0.f, 0.f, 0.f};

  k5f_stage(w, lane, 0, l0, GTHI, GTLO, YHI, YLO, Ah[0], Al[0], Bh[0], Bl[0]);

  #pragma unroll 1
  for (int step = 0; step < 64; ++step) {
    int cur = step & 1;
    __syncthreads();   // DMA of buf cur complete (vmcnt drained) + prior reads of buf cur^1 done
    if (step < 63)
      k5f_stage(w, lane, (step + 1) * 32, l0, GTHI, GTLO, YHI, YLO,
                Ah[cur ^ 1], Al[cur ^ 1], Bh[cur ^ 1], Bl[cur ^ 1]);
    short8v ahf[4], alf[4], bhf[4], blf[4];
    #pragma unroll
    for (int mt = 0; mt < 4; ++mt) {
      int o = (mt * 16 + row16) * 32 + quad * 8;
      ahf[mt] = *(const short8v*)&Ah[cur][o];
      alf[mt] = *(const short8v*)&Al[cur][o];
    }
    #pragma unroll
    for (int nt = 0; nt < 4; ++nt) {
      int o = (w * 64 + nt * 16 + row16) * 32 + quad * 8;
      bhf[nt] = *(const short8v*)&Bh[cur][o];
      blf[nt] = *(const short8v*)&Bl[cur][o];
    }
    #pragma unroll
    for (int nt = 0; nt < 4; ++nt) {
      #pragma unroll
      for (int mt = 0; mt < 4; ++mt) {
        acc[mt][nt] = __builtin_amdgcn_mfma_f32_16x16x32_bf16(ahf[mt], bhf[nt], acc[mt][nt], 0, 0, 0);
        acc[mt][nt] = __builtin_amdgcn_mfma_f32_16x16x32_bf16(ahf[mt], blf[nt], acc[mt][nt], 0, 0, 0);
        acc[mt][nt] = __builtin_amdgcn_mfma_f32_16x16x32_bf16(alf[mt], bhf[nt], acc[mt][nt], 0, 0, 0);
      }
    }
  }

  // epilogue: each wave owns r-range [w*64, w*64+64); max over its 64 l's
  float rl_[4][4];
  #pragma unroll
  for (int mt = 0; mt < 4; ++mt)
    #pragma unroll
    for (int q = 0; q < 4; ++q)
      rl_[mt][q] = rgg[l0 + mt * 16 + quad * 4 + q];
  #pragma unroll
  for (int nt = 0; nt < 4; ++nt) {
    float m = 0.f;
    #pragma unroll
    for (int mt = 0; mt < 4; ++mt)
      #pragma unroll
      for (int q = 0; q < 4; ++q) {
        float U = acc[mt][nt][q];
        m = fmaxf(m, U * U * rl_[mt][q]);
      }
    m = fmaxf(m, __shfl_xor(m, 16, 64));
    m = fmaxf(m, __shfl_xor(m, 32, 64));
    int r = w * 64 + nt * 16 + row16;
    if (quad == 0 && r < R_PERM) atomicMax(&s[r], __float_as_uint(m));
  }
}

// ================= K6: TS^2 -> p -> MoM + lane-parallel Newton -> betainc =====
__global__ __launch_bounds__(256) void k6_final(
    const unsigned* __restrict__ sbits, const float* __restrict__ yty,
    const float* __restrict__ minp, float* __restrict__ out) {
  __shared__ double red[256];
  int tid = threadIdx.x;
  double p = 0.0, p2 = 0.0, lp = 0.0, l1p = 0.0;
  if (tid < R_PERM) {
    double t = (double)__uint_as_float(sbits[tid]);
    double Y = (double)yty[tid];
    double ts2 = DOF_D * t / (Y - t);
    double pp = erfc(sqrt(0.5 * ts2));
    p = pp; p2 = pp * pp; lp = log(pp); l1p = log1p(-pp);
  }
  double Sp  = breduce_add(p, red, tid);
  double Sp2 = breduce_add(p2, red, tid);
  double S1  = breduce_add(lp, red, tid);
  double S2  = breduce_add(l1p, red, tid);
  if (tid < 64) {
    const double nobs = (double)R_PERM;
    double mean = Sp / nobs;
    double var = Sp2 / nobs - mean * mean;
    double k = mean * (mean * (1.0 - mean) / var - 1.0);
    double n = k * (1.0 / mean - 1.0);
    double old_lik = 10000.0, diff = 1000.0;
    int iter = 0;
    int sel = tid % 3, grp = tid / 3;
    while (fabs(diff) > 1e-3 && iter <= 100) {
      double arg = (sel == 0) ? k : (sel == 1) ? n : (k + n);
      double v = 0.0;
      if (grp == 0) v = dg_trigamma(arg);
      else if (grp == 1) v = dg_tetragamma(arg);
      else if (grp == 2) v = dg_digamma(arg);
      double pg1k = __shfl(v, 0, 64), pg1n = __shfl(v, 1, 64), pg1kn = __shfl(v, 2, 64);
      double pg2k = __shfl(v, 3, 64), pg2n = __shfl(v, 4, 64), pg2kn = __shfl(v, 5, 64);
      double dgk  = __shfl(v, 6, 64), dgn  = __shfl(v, 7, 64), dgkn  = __shfl(v, 8, 64);
      double i_kn = -pg1kn, i_k = pg1k + i_kn, i_n = pg1n + i_kn;
      double A = -nobs * i_k, B = -nobs * i_kn, C = -nobs * i_n;
      double s0 = S1 - nobs * (dgk - dgkn);
      double s1 = S2 - nobs * (dgn - dgkn);
      double det = A * C - B * B;
      double d0 = (C * s0 - B * s1) / det;
      double d1 = (A * s1 - B * s0) / det;
      double i_kkn = pg1n * pg2kn;
      double g_k = -pg1n * pg2k + i_kkn + pg1kn * pg2k;
      double i_knn = i_kkn - pg1kn * pg2n;
      double i_nnk = pg1k * pg2kn;
      double i_nkk = i_nnk - pg1kn * pg2k;
      double g_n = -pg1k * pg2n + i_nnk + pg1kn * pg2n;
      double scale = -pg1k * pg1n + (pg1k + pg1n) * pg1kn;
      double f = 0.5 / scale;
      double adj0 = f * (g_k * d0 * d0 + 2.0 * i_kkn * d0 * d1 + i_knn * d1 * d1);
      double adj1 = f * (i_nkk * d0 * d0 + 2.0 * i_nnk * d0 * d1 + g_n * d1 * d1);
      double nk_ = k - d0 - 0.5 * adj0;
      double nn_ = n - d1 - 0.5 * adj1;
      double arg2 = (tid == 0) ? nk_ : (tid == 1) ? nn_ : (nk_ + nn_);
      double lg = (tid < 3) ? lgamma(arg2) : 0.0;
      double lgk = __shfl(lg, 0, 64), lgn = __shfl(lg, 1, 64), lgkn = __shfl(lg, 2, 64);
      double nl = (nk_ - 1.0) * S1 + (nn_ - 1.0) * S2 - nobs * (lgk + lgn - lgkn);
      diff = old_lik - nl;
      old_lik = nl; k = nk_; n = nn_; ++iter;
    }
    if (tid == 0) {
      double conv = (fabs(diff) < 1e-3 && iter <= 100) ? 1.0 : 0.0;
      double adj = betainc_d(k, n, (double)(*minp));
      out[0] = (float)adj;
      out[1] = (float)k;
      out[2] = (float)n;
      out[3] = (float)conv;
    }
  }
}

__global__ void k_err(float* out) {
  if (threadIdx.x < 4) out[threadIdx.x] = -12345.0f;
}

extern "C" void kernel_launch(void* const* d_in, const int* in_sizes, int n_in,
                              void* d_out, int out_size, void* d_ws, size_t ws_size,
                              hipStream_t stream) {
  const float* X     = (const float*)d_in[0];
  const float* y     = (const float*)d_in[1];
  const float* G     = (const float*)d_in[2];
  const float* obs_p = (const float*)d_in[3];
  const float* offs  = (const float*)d_in[4];
  const int*   seedp = (const int*)d_in[5];
  float* out = (float*)d_out;

  if (ws_size < WS_OLD) {
    k_err<<<1, 64, 0, stream>>>(out);
    return;
  }
  char* ws = (char*)d_ws;
  unsigned* pkeys = (unsigned*)(ws + OFF_PKEYS);
  double*   Mi    = (double*)(ws + OFF_MI);
  float*    minp  = (float*)(ws + OFF_MINP);
  float*    Xt    = (float*)(ws + OFF_XT);
  float*    XtGp  = (float*)(ws + OFF_XTGP);
  float*    GGp   = (float*)(ws + OFF_GGP);
  float*    gg    = (float*)(ws + OFF_GG);
  float*    yty   = (float*)(ws + OFF_YTY);
  unsigned* s     = (unsigned*)(ws + OFF_S);
  float*    Yt    = (float*)(ws + OFF_YT);

  bool big = (ws_size >= WS_BIG);
  float*          rgg   = big ? (float*)(ws + OFF_RGG) : nullptr;
  unsigned short* yhi   = big ? (unsigned short*)(ws + OFF_YHI) : nullptr;
  unsigned short* ylo   = big ? (unsigned short*)(ws + OFF_YLO) : nullptr;
  float*          XtGp2 = big ? (float*)(ws + OFF_XTGP2) : nullptr;
  float*          GGp2  = big ? (float*)(ws + OFF_GGP2) : nullptr;
  unsigned short* GTHI  = big ? (unsigned short*)(ws + OFF_GTHI) : nullptr;
  unsigned short* GTLO  = big ? (unsigned short*)(ws + OFF_GTLO) : nullptr;

  if (big) {
    k1_setup<<<3 + (RPAD - R_PERM), 256, 0, stream>>>(X, obs_p, Xt, Mi, minp, yhi, ylo);
    k2t_pass<<<dim3(158, 16), 256, 0, stream>>>(G, X, seedp, GTHI, GTLO, XtGp2, GGp2, pkeys);
    k3t_gg<<<40, 256, 0, stream>>>(XtGp2, GGp2, Mi, gg, rgg);
    // big path: skip fallback-Yt write (region overlaps YHI) -> pass nullptr
    k4_perm<<<R_PERM, 1024, 0, stream>>>(y, offs, Xt, pkeys, Mi, nullptr, yty, s, yhi, ylo);
    k5f_mfma<<<157, 256, 0, stream>>>(GTHI, GTLO, yhi, ylo, rgg, s);
  } else {
    k1_setup<<<3, 256, 0, stream>>>(X, obs_p, Xt, Mi, minp, nullptr, nullptr);
    k2_xtg<<<dim3(41, 5), 256, 0, stream>>>(G, X, seedp, XtGp, GGp, pkeys);
    k3_gg<<<40, 256, 0, stream>>>(XtGp, GGp, Mi, gg);
    k4_perm<<<R_PERM, 1024, 0, stream>>>(y, offs, Xt, pkeys, Mi, Yt, yty, s, nullptr, nullptr);
    k5_gemm<<<dim3(157, 4), 256, 0, stream>>>(G, Yt, gg, s);
  }
  k6_final<<<1, 256, 0, stream>>>(s, yty, minp, out);
}